// Round 5
// baseline (704.333 us; speedup 1.0000x reference)
//
#include <hip/hip_runtime.h>
#include <hip/hip_cooperative_groups.h>
#include <math.h>

#define CCH 192
#define EPS 1e-5f
#define NBLK 1536            // 6 blocks/CU * 256 CU
#define POOLB 1480           // blocks [0,1480) pool(+pack); [1480,1536) gate
#define GSTR (NBLK * 256)    // 393216 threads

typedef float vfloat4 __attribute__((ext_vector_type(4)));

namespace cg = cooperative_groups;

__device__ __constant__ int d_LOWX[32] = {0,0,1,1,0,2,2,1,2,0,3,4,0,1,3,0,1,2,3,4,5,0,1,2,3,4,5,6,1,2,3,4};
__device__ __constant__ int d_LOWY[32] = {0,1,0,1,2,0,1,2,2,3,0,0,4,3,1,5,4,3,2,1,0,6,5,4,3,2,1,0,6,5,4,3};

// ---------------- single cooperative kernel: 3 phases ----------------
// MLP discipline: every load group is issued in full, then sched_barrier(0),
// then consumed — compiler cannot serialize loads down to the use site.
__global__ __launch_bounds__(256, 6) void fused_all(
    const float* __restrict__ x, const float* __restrict__ wg1,
    const float* __restrict__ bn2_g, const float* __restrict__ bn2_b,
    const float* __restrict__ bn2_m, const float* __restrict__ bn2_v,
    const float* __restrict__ wg2, const float* __restrict__ bg2,
    const float* __restrict__ beta, const float* __restrict__ w1d,
    const float* __restrict__ b1d,
    const float* __restrict__ bn1_g, const float* __restrict__ bn1_b,
    const float* __restrict__ bn1_m, const float* __restrict__ bn1_v,
    float* __restrict__ out,
    float* __restrict__ partial, float* __restrict__ wt,
    float* __restrict__ xp, float* __restrict__ scale) {
  cg::grid_group grid = cg::this_grid();
  __shared__ float smem[4 * 49];
  __shared__ float gm[32], xg[32], param[33], Btab[49], yl[CCH];
  const int b = blockIdx.x, t = threadIdx.x;

  // ================= phase 1 =================
  if (b >= POOLB) {
    // ---- gate role (n=0): one h row per block; wave wv owns outputs [8wv,8wv+8)
    const int h = b - POOLB;
    const int wv = t >> 6, w = t & 63;
    float acc[8];
#pragma unroll
    for (int o = 0; o < 8; ++o) acc[o] = 0.f;
    const float* xrow = x + h * 56;               // x[c*3136 + h*56 + w]
    for (int cc0 = 0; cc0 < CCH; cc0 += 8) {
      float xq[8];
#pragma unroll
      for (int j = 0; j < 8; ++j)
        xq[j] = (w < 56) ? xrow[(size_t)(cc0 + j) * 3136 + w] : 0.f;
      __builtin_amdgcn_sched_barrier(0);          // keep all 8 loads issued together
#pragma unroll
      for (int j = 0; j < 8; ++j)
#pragma unroll
        for (int o = 0; o < 8; ++o)
          acc[o] += xq[j] * wg1[(wv * 8 + o) * CCH + cc0 + j];  // uniform -> s_load
    }
#pragma unroll
    for (int o = 0; o < 8; ++o) {
      const int oo = wv * 8 + o;
      float sc = bn2_g[oo] * rsqrtf(bn2_v[oo] + EPS);
      float v = acc[o] * sc + (bn2_b[oo] - bn2_m[oo] * sc);
      v = (w < 56) ? fmaxf(v, 0.f) : 0.f;         // BN offset must not leak into pad lanes
#pragma unroll
      for (int s = 1; s < 64; s <<= 1) v += __shfl_xor(v, s);
      if (w == 0) partial[h * 32 + oo] = v;
    }
  } else {
    if (b < 144) {
      // ---- pack role: i in [0, 36864)
      const int i = b * 256 + t;
      const int cc = i / CCH, k = i - cc * CCH;
      wt[k * CCH + cc] = w1d[cc * (CCH * 3) + 3 * k + 1];
    }
    // ---- pool role: units u (3072 total): 4 waves, one channel per wave
    for (int u = b; u < 3072; u += POOLB) {
      const int n = u / 48, c0 = (u % 48) * 4;
      const int wv = t >> 6, l = t & 63;
      const int c = c0 + wv;
      const bool act = l < 56;
      const int lidx = act ? l : 0;
      const vfloat4* xv = (const vfloat4*)(x + (size_t)(n * CCH + c) * 3136);
      vfloat4 va[7], vb[7];
#pragma unroll
      for (int g = 0; g < 7; ++g) {
        va[g] = xv[g * 112 + lidx];
        vb[g] = xv[g * 112 + 56 + lidx];
      }
      __builtin_amdgcn_sched_barrier(0);          // force all 14 loads in flight
      float as[7];
#pragma unroll
      for (int g = 0; g < 7; ++g) {
        float s = (va[g].x + va[g].y + va[g].z + va[g].w) +
                  (vb[g].x + vb[g].y + vb[g].z + vb[g].w);
        as[g] = act ? s : 0.f;
      }
      __syncthreads();          // WAR: previous unit's smem[t<196] read must finish
#pragma unroll
      for (int g = 0; g < 7; ++g) {
        float a = as[g] + __shfl_xor(as[g], 1);
        a += __shfl(a, l + 28);
        a += __shfl(a, l + 14);
        if (act && l < 14 && (l & 1) == 0)
          smem[wv * 49 + g * 7 + (l >> 1)] = a;
      }
      __syncthreads();
      if (t < 196) xp[((size_t)n * CCH + c0) * 49 + t] = smem[t] * (1.f / 64.f);
    }
  }

  grid.sync();

  // ================= phase 2 (blocks 0..63, n = b) =================
  if (b < 64) {
    const int n = b;
    if (t < 32) {
      float s = 0.f;
      for (int hh = 0; hh < 56; ++hh) s += partial[hh * 32 + t];  // sequential: bit-stable
      gm[t] = s * (1.f / 3136.f);
    }
    if (t < 49) {
      int f = t / 7, tt = t % 7;
      float r = cosf(3.14159265358979323846f * (float)f * ((float)tt + 0.5f) / 7.f) * rsqrtf(7.f);
      Btab[t] = (f == 0) ? r : r * sqrtf(2.f);
    }
    __syncthreads();
    if (t < 32) {
      float a = bg2[t];
      for (int k = 0; k < 32; ++k) a += gm[k] * wg2[t * 32 + k];
      xg[t] = fmaxf(tanhf(a), 0.f) + beta[0];
    }
    __syncthreads();
    if (t == 0) {
      float s = 0.f;
      for (int k = 0; k < 32; ++k) s += xg[k];
      float psum = 0.f;
      param[0] = 0.f;
      for (int i = 0; i < 31; ++i) {
        float p = rintf(xg[i] / s * (float)CCH);  // nearest-even, matches jnp.round
        param[i + 1] = p;
        psum += p;
      }
      param[32] = (float)CCH - psum;
    }
    __syncthreads();
    if (t < CCH) {
      int bi = -1;
      float cf = (float)t;
      for (int i = 0; i < 32; ++i)
        if (cf >= param[i] && cf < param[i + 1]) bi = i;  // last match wins
      int fx = (bi >= 0) ? d_LOWX[bi] : 0;
      int fy = (bi >= 0) ? d_LOWY[bi] : 0;
      const float* xc = xp + ((size_t)n * CCH + t) * 49;
      float s = 0.f;
      for (int cell = 0; cell < 49; ++cell) {
        int a = cell / 7, bb = cell - a * 7;
        float w = Btab[fx * 7 + a] * Btab[fy * 7 + bb];  // same product order as filt build
        s += xc[cell] * ((bi >= 0) ? w : 0.f);
      }
      yl[t] = s;
    }
    __syncthreads();
    if (t < CCH) {
      float acc = b1d[t];
#pragma unroll 8
      for (int k = 0; k < CCH; ++k) acc += yl[k] * wt[k * CCH + t];
      float sc = bn1_g[t] * rsqrtf(bn1_v[t] + EPS);
      float v = (acc - bn1_m[t]) * sc + bn1_b[t];
      scale[n * CCH + t] = 1.f + fmaxf(v, 0.f);
    }
  }

  grid.sync();

  // ================= phase 3: apply (grid-stride, 8-deep load batches) =============
  // 9,633,792 float4 = 24 full strides of GSTR + tail 196608.
  {
    const int gid = b * 256 + t;                  // < 393216
    const vfloat4* __restrict__ xv = (const vfloat4*)x;
    vfloat4* __restrict__ ov = (vfloat4*)out;
#pragma unroll
    for (int B = 0; B < 3; ++B) {                 // batches k = 8B .. 8B+7
      vfloat4 vv[8];
#pragma unroll
      for (int j = 0; j < 8; ++j) vv[j] = xv[gid + (B * 8 + j) * GSTR];
      __builtin_amdgcn_sched_barrier(0);          // 8 loads in flight before any store
#pragma unroll
      for (int j = 0; j < 8; ++j) {
        const int f = gid + (B * 8 + j) * GSTR;
        ov[f] = vv[j] * scale[f / 784];           // 784 float4s per (n,c)
      }
    }
    if (gid < 9633792 - 24 * GSTR) {              // tail: 196608
      const int f = gid + 24 * GSTR;
      ov[f] = xv[f] * scale[f / 784];
    }
  }
}

// ---------------- fallback path (proven 3-kernel pipeline) ----------------
__global__ __launch_bounds__(256) void fused_pre_kernel(
    const float* __restrict__ x, const float* __restrict__ w1d,
    const float* __restrict__ wg1,
    const float* __restrict__ bn2_g, const float* __restrict__ bn2_b,
    const float* __restrict__ bn2_m, const float* __restrict__ bn2_v,
    float* __restrict__ xp, float* __restrict__ wt, float* __restrict__ partial) {
  __shared__ float smem[4 * 49];
  const int b = blockIdx.x;
  const int t = threadIdx.x;
  if (b >= 200) {
    const int pb = b - 200;
    const int n = pb / 48, c0 = (pb % 48) * 4;
    const int wv = t >> 6, l = t & 63;
    const int c = c0 + wv;
    const bool act = l < 56;
    const int lidx = act ? l : 0;
    const vfloat4* xv = (const vfloat4*)(x + (size_t)(n * CCH + c) * 3136);
    vfloat4 va[7], vb[7];
#pragma unroll
    for (int g = 0; g < 7; ++g) {
      va[g] = xv[g * 112 + lidx];
      vb[g] = xv[g * 112 + 56 + lidx];
    }
    float as[7];
#pragma unroll
    for (int g = 0; g < 7; ++g) {
      float s = (va[g].x + va[g].y + va[g].z + va[g].w) +
                (vb[g].x + vb[g].y + vb[g].z + vb[g].w);
      as[g] = act ? s : 0.f;
    }
#pragma unroll
    for (int g = 0; g < 7; ++g) {
      float a = as[g] + __shfl_xor(as[g], 1);
      a += __shfl(a, l + 28);
      a += __shfl(a, l + 14);
      if (act && l < 14 && (l & 1) == 0)
        smem[wv * 49 + g * 7 + (l >> 1)] = a;
    }
    __syncthreads();
    if (t < 196) xp[((size_t)n * CCH + c0) * 49 + t] = smem[t] * (1.f / 64.f);
  } else if (b >= 56) {
    const int i = (b - 56) * 256 + t;
    const int cc = i / CCH, k = i - cc * CCH;
    wt[k * CCH + cc] = w1d[cc * (CCH * 3) + 3 * k + 1];
  } else {
    const int h = b;
    const int wv = t >> 6, w = t & 63;
    float acc[8];
#pragma unroll
    for (int o = 0; o < 8; ++o) acc[o] = 0.f;
    const float* xrow = x + h * 56;
    for (int cc0 = 0; cc0 < CCH; cc0 += 8) {
      float xq[8];
#pragma unroll
      for (int j = 0; j < 8; ++j)
        xq[j] = (w < 56) ? xrow[(size_t)(cc0 + j) * 3136 + w] : 0.f;
#pragma unroll
      for (int j = 0; j < 8; ++j)
#pragma unroll
        for (int o = 0; o < 8; ++o)
          acc[o] += xq[j] * wg1[(wv * 8 + o) * CCH + cc0 + j];
    }
#pragma unroll
    for (int o = 0; o < 8; ++o) {
      const int oo = wv * 8 + o;
      float sc = bn2_g[oo] * rsqrtf(bn2_v[oo] + EPS);
      float v = acc[o] * sc + (bn2_b[oo] - bn2_m[oo] * sc);
      v = (w < 56) ? fmaxf(v, 0.f) : 0.f;
#pragma unroll
      for (int s = 1; s < 64; s <<= 1) v += __shfl_xor(v, s);
      if (w == 0) partial[h * 32 + oo] = v;
    }
  }
}

__global__ __launch_bounds__(256) void scale_kernel(
    const float* __restrict__ partial, const float* __restrict__ wg2,
    const float* __restrict__ bg2, const float* __restrict__ beta,
    const float* __restrict__ xp, const float* __restrict__ wt,
    const float* __restrict__ b1d,
    const float* __restrict__ bn1_g, const float* __restrict__ bn1_b,
    const float* __restrict__ bn1_m, const float* __restrict__ bn1_v,
    float* __restrict__ scale) {
  __shared__ float gm[32];
  __shared__ float xg[32];
  __shared__ float param[33];
  __shared__ float Btab[49];
  __shared__ float yl[CCH];
  const int n = blockIdx.x, t = threadIdx.x;
  if (t < 32) {
    float s = 0.f;
    for (int hh = 0; hh < 56; ++hh) s += partial[hh * 32 + t];
    gm[t] = s * (1.f / 3136.f);
  }
  if (t < 49) {
    int f = t / 7, tt = t % 7;
    float r = cosf(3.14159265358979323846f * (float)f * ((float)tt + 0.5f) / 7.f) * rsqrtf(7.f);
    Btab[t] = (f == 0) ? r : r * sqrtf(2.f);
  }
  __syncthreads();
  if (t < 32) {
    float a = bg2[t];
    for (int k = 0; k < 32; ++k) a += gm[k] * wg2[t * 32 + k];
    xg[t] = fmaxf(tanhf(a), 0.f) + beta[0];
  }
  __syncthreads();
  if (t == 0) {
    float s = 0.f;
    for (int k = 0; k < 32; ++k) s += xg[k];
    float psum = 0.f;
    param[0] = 0.f;
    for (int i = 0; i < 31; ++i) {
      float p = rintf(xg[i] / s * (float)CCH);
      param[i + 1] = p;
      psum += p;
    }
    param[32] = (float)CCH - psum;
  }
  __syncthreads();
  if (t < CCH) {
    int bi = -1;
    float cf = (float)t;
    for (int i = 0; i < 32; ++i)
      if (cf >= param[i] && cf < param[i + 1]) bi = i;
    int fx = (bi >= 0) ? d_LOWX[bi] : 0;
    int fy = (bi >= 0) ? d_LOWY[bi] : 0;
    const float* xc = xp + ((size_t)n * CCH + t) * 49;
    float s = 0.f;
    for (int cell = 0; cell < 49; ++cell) {
      int a = cell / 7, bb = cell - a * 7;
      float w = Btab[fx * 7 + a] * Btab[fy * 7 + bb];
      s += xc[cell] * ((bi >= 0) ? w : 0.f);
    }
    yl[t] = s;
  }
  __syncthreads();
  if (t < CCH) {
    float acc = b1d[t];
#pragma unroll 8
    for (int k = 0; k < CCH; ++k) acc += yl[k] * wt[k * CCH + t];
    float sc = bn1_g[t] * rsqrtf(bn1_v[t] + EPS);
    float v = (acc - bn1_m[t]) * sc + bn1_b[t];
    scale[n * CCH + t] = 1.f + fmaxf(v, 0.f);
  }
}

__global__ __launch_bounds__(256) void apply_kernel(
    const float* __restrict__ x, const float* __restrict__ scale,
    float* __restrict__ out) {
  const int base = blockIdx.x * 2048 + threadIdx.x;
  const vfloat4* __restrict__ xv = (const vfloat4*)x;
  vfloat4* __restrict__ ov = (vfloat4*)out;
#pragma unroll
  for (int k = 0; k < 8; ++k) {
    const int f = base + k * 256;
    const float s = scale[f / 784];
    vfloat4 v = xv[f];
    ov[f] = v * s;
  }
}

extern "C" void kernel_launch(void* const* d_in, const int* in_sizes, int n_in,
                              void* d_out, int out_size, void* d_ws, size_t ws_size,
                              hipStream_t stream) {
  const float* x     = (const float*)d_in[0];
  const float* wg1   = (const float*)d_in[1];
  const float* bn2_g = (const float*)d_in[2];
  const float* bn2_b = (const float*)d_in[3];
  const float* bn2_m = (const float*)d_in[4];
  const float* bn2_v = (const float*)d_in[5];
  const float* wg2   = (const float*)d_in[6];
  const float* bg2   = (const float*)d_in[7];
  const float* beta  = (const float*)d_in[8];
  const float* w1d   = (const float*)d_in[9];
  const float* b1d   = (const float*)d_in[10];
  const float* bn1_g = (const float*)d_in[11];
  const float* bn1_b = (const float*)d_in[12];
  const float* bn1_m = (const float*)d_in[13];
  const float* bn1_v = (const float*)d_in[14];
  float* out = (float*)d_out;

  float* ws      = (float*)d_ws;
  float* partial = ws;                   // 56*32      = 1792
  float* filt    = partial + 1792;       // (slot kept for layout stability)
  float* wt      = filt + 9408;          // 192*192    = 36864
  float* xp      = wt + 36864;           // 64*192*49  = 602112
  float* scale   = xp + 602112;          // 64*192     = 12288

  static int coop = -1;
  if (coop < 0) {
    int dev = 0, v = 0;
    hipGetDevice(&dev);
    hipDeviceGetAttribute(&v, hipDeviceAttributeCooperativeLaunch, dev);
    coop = v;
  }

  hipError_t e = hipErrorUnknown;
  if (coop) {
    void* args[] = {(void*)&x, (void*)&wg1, (void*)&bn2_g, (void*)&bn2_b,
                    (void*)&bn2_m, (void*)&bn2_v, (void*)&wg2, (void*)&bg2,
                    (void*)&beta, (void*)&w1d, (void*)&b1d, (void*)&bn1_g,
                    (void*)&bn1_b, (void*)&bn1_m, (void*)&bn1_v, (void*)&out,
                    (void*)&partial, (void*)&wt, (void*)&xp, (void*)&scale};
    e = hipLaunchCooperativeKernel((const void*)fused_all, dim3(NBLK), dim3(256),
                                   args, 0, stream);
  }
  if (e != hipSuccess) {
    fused_pre_kernel<<<3272, 256, 0, stream>>>(x, w1d, wg1, bn2_g, bn2_b, bn2_m, bn2_v,
                                               xp, wt, partial);
    scale_kernel<<<64, 256, 0, stream>>>(partial, wg2, bg2, beta, xp, wt, b1d,
                                         bn1_g, bn1_b, bn1_m, bn1_v, scale);
    apply_kernel<<<4704, 256, 0, stream>>>(x, scale, out);
  }
}

// Round 6
// 345.236 us; speedup vs baseline: 2.0402x; 2.0402x over previous
//
#include <hip/hip_runtime.h>
#include <hip/hip_bf16.h>
#include <math.h>

#define CCH 192
#define EPS 1e-5f

typedef float vfloat4 __attribute__((ext_vector_type(4)));

__device__ __constant__ int d_LOWX[32] = {0,0,1,1,0,2,2,1,2,0,3,4,0,1,3,0,1,2,3,4,5,0,1,2,3,4,5,6,1,2,3,4};
__device__ __constant__ int d_LOWY[32] = {0,1,0,1,2,0,1,2,2,3,0,0,4,3,1,5,4,3,2,1,0,6,5,4,3,2,1,0,6,5,4,3};

// Force a global load that stays in flight: asm output forces register liveness,
// so the compiler cannot serialize the batch down to the use site.
#define GLOAD4(dst, addr) \
  asm volatile("global_load_dwordx4 %0, %1, off" : "=v"(dst) : "v"(addr))
#define GLOAD1(dst, addr) \
  asm volatile("global_load_dword %0, %1, off" : "=v"(dst) : "v"(addr))
#define VMWAIT0() do { \
  asm volatile("s_waitcnt vmcnt(0)" ::: "memory"); \
  __builtin_amdgcn_sched_barrier(0); \
} while (0)

// ---------------- K1: fused pre-pass, one launch, three block roles ----------------
//  blocks [0,56):     gate conv rows for n=0 -> partial[h][32]
//  blocks [56,200):   pack wt[k*192+c] = w1d[c][k][1]
//  blocks [200,3272): unweighted adaptive pool x -> xp[n][c][49], 14 loads forced in flight
__global__ __launch_bounds__(256) void fused_pre_kernel(
    const float* __restrict__ x, const float* __restrict__ w1d,
    const float* __restrict__ wg1,
    const float* __restrict__ bn2_g, const float* __restrict__ bn2_b,
    const float* __restrict__ bn2_m, const float* __restrict__ bn2_v,
    float* __restrict__ xp, float* __restrict__ wt, float* __restrict__ partial) {
  __shared__ float smem[4 * 49];
  const int b = blockIdx.x;
  const int t = threadIdx.x;
  if (b >= 200) {
    // ---- pool role: 4 waves, one channel per wave; 14 asm loads in flight per wave.
    const int pb = b - 200;
    const int n = pb / 48, c0 = (pb % 48) * 4;
    const int wv = t >> 6, l = t & 63;
    const int c = c0 + wv;
    const bool act = l < 56;
    const int lidx = act ? l : 0;      // keep OOB lanes safe
    const vfloat4* xv = (const vfloat4*)(x + (size_t)(n * CCH + c) * 3136);
    vfloat4 va[7], vb[7];
#pragma unroll
    for (int g = 0; g < 7; ++g) {
      GLOAD4(va[g], xv + g * 112 + lidx);
      GLOAD4(vb[g], xv + g * 112 + 56 + lidx);
    }
    VMWAIT0();
    float as[7];
#pragma unroll
    for (int g = 0; g < 7; ++g) {
      float s = (va[g].x + va[g].y + va[g].z + va[g].w) +
                (vb[g].x + vb[g].y + vb[g].z + vb[g].w);
      as[g] = act ? s : 0.f;
    }
#pragma unroll
    for (int g = 0; g < 7; ++g) {
      // pair lanes (wq even, wq odd) -> 8-col sum for rows {r, r+4}
      float a = as[g] + __shfl_xor(as[g], 1);
      a += __shfl(a, l + 28);          // r with r+2
      a += __shfl(a, l + 14);          // r(0,1) pairs
      if (act && l < 14 && (l & 1) == 0)
        smem[wv * 49 + g * 7 + (l >> 1)] = a;
    }
    __syncthreads();
    if (t < 196) xp[((size_t)n * CCH + c0) * 49 + t] = smem[t] * (1.f / 64.f);
  } else if (b >= 56) {
    // ---- pack role
    const int i = (b - 56) * 256 + t;             // < 36864
    const int cc = i / CCH, k = i - cc * CCH;
    wt[k * CCH + cc] = w1d[cc * (CCH * 3) + 3 * k + 1];
  } else {
    // ---- gate role (n=0): one h row per block; wave wv owns outputs [8wv,8wv+8)
    const int h = b;
    const int wv = t >> 6, w = t & 63;
    float acc[8];
#pragma unroll
    for (int o = 0; o < 8; ++o) acc[o] = 0.f;
    const float* xrow = x + h * 56;               // x[c*3136 + h*56 + w]
    for (int cc0 = 0; cc0 < CCH; cc0 += 8) {
      float xq[8];
#pragma unroll
      for (int j = 0; j < 8; ++j)
        GLOAD1(xq[j], xrow + (size_t)(cc0 + j) * 3136 + ((w < 56) ? w : 0));
      VMWAIT0();
#pragma unroll
      for (int j = 0; j < 8; ++j) {
        float xvv = (w < 56) ? xq[j] : 0.f;
#pragma unroll
        for (int o = 0; o < 8; ++o)
          acc[o] += xvv * wg1[(wv * 8 + o) * CCH + cc0 + j];  // uniform -> s_load
      }
    }
#pragma unroll
    for (int o = 0; o < 8; ++o) {
      const int oo = wv * 8 + o;
      float sc = bn2_g[oo] * rsqrtf(bn2_v[oo] + EPS);
      float v = acc[o] * sc + (bn2_b[oo] - bn2_m[oo] * sc);
      v = (w < 56) ? fmaxf(v, 0.f) : 0.f;         // BN offset must not leak into pad lanes
#pragma unroll
      for (int s = 1; s < 64; s <<= 1) v += __shfl_xor(v, s);
      if (w == 0) partial[h * 32 + oo] = v;
    }
  }
}

// ---------------- K2: merged mid+gemv: partial -> xg0 -> param -> filt -> scale ----------
__global__ __launch_bounds__(256) void scale_kernel(
    const float* __restrict__ partial, const float* __restrict__ wg2,
    const float* __restrict__ bg2, const float* __restrict__ beta,
    const float* __restrict__ xp, const float* __restrict__ wt,
    const float* __restrict__ b1d,
    const float* __restrict__ bn1_g, const float* __restrict__ bn1_b,
    const float* __restrict__ bn1_m, const float* __restrict__ bn1_v,
    float* __restrict__ scale) {
  __shared__ float gm[32];
  __shared__ float xg[32];
  __shared__ float param[33];
  __shared__ float Btab[49];
  __shared__ float yl[CCH];
  const int n = blockIdx.x, t = threadIdx.x;
  if (t < 32) {
    float s = 0.f;
    for (int hh = 0; hh < 56; ++hh) s += partial[hh * 32 + t];  // sequential: bit-stable
    gm[t] = s * (1.f / 3136.f);
  }
  if (t < 49) {
    int f = t / 7, tt = t % 7;
    float r = cosf(3.14159265358979323846f * (float)f * ((float)tt + 0.5f) / 7.f) * rsqrtf(7.f);
    Btab[t] = (f == 0) ? r : r * sqrtf(2.f);
  }
  __syncthreads();
  if (t < 32) {
    float a = bg2[t];
    for (int k = 0; k < 32; ++k) a += gm[k] * wg2[t * 32 + k];
    xg[t] = fmaxf(tanhf(a), 0.f) + beta[0];
  }
  __syncthreads();
  if (t == 0) {
    float s = 0.f;
    for (int k = 0; k < 32; ++k) s += xg[k];
    float psum = 0.f;
    param[0] = 0.f;
    for (int i = 0; i < 31; ++i) {
      float p = rintf(xg[i] / s * (float)CCH);  // nearest-even, matches jnp.round
      param[i + 1] = p;
      psum += p;
    }
    param[32] = (float)CCH - psum;
  }
  __syncthreads();
  if (t < CCH) {
    int bi = -1;
    float cf = (float)t;
    for (int i = 0; i < 32; ++i)
      if (cf >= param[i] && cf < param[i + 1]) bi = i;  // last match wins
    int fx = (bi >= 0) ? d_LOWX[bi] : 0;
    int fy = (bi >= 0) ? d_LOWY[bi] : 0;
    const float* xc = xp + ((size_t)n * CCH + t) * 49;
    float s = 0.f;
    for (int cell = 0; cell < 49; ++cell) {
      int a = cell / 7, bb = cell - a * 7;
      float w = Btab[fx * 7 + a] * Btab[fy * 7 + bb];  // same product order as filt build
      s += xc[cell] * ((bi >= 0) ? w : 0.f);
    }
    yl[t] = s;
  }
  __syncthreads();
  if (t < CCH) {
    float acc = b1d[t];
#pragma unroll 8
    for (int k = 0; k < CCH; ++k) acc += yl[k] * wt[k * CCH + t];
    float sc = bn1_g[t] * rsqrtf(bn1_v[t] + EPS);
    float v = (acc - bn1_m[t]) * sc + bn1_b[t];
    scale[n * CCH + t] = 1.f + fmaxf(v, 0.f);
  }
}

// ---------------- K3: out = x * scale[n,c] ----------------
// 8 x-loads + 8 scale-loads per thread forced in flight via asm, then 8 stores.
__global__ __launch_bounds__(256) void apply_kernel(
    const float* __restrict__ x, const float* __restrict__ scale,
    float* __restrict__ out) {
  const int base = blockIdx.x * 2048 + threadIdx.x;  // 4704*2048 = 9,633,792 float4s
  const vfloat4* __restrict__ xv = (const vfloat4*)x;
  vfloat4* __restrict__ ov = (vfloat4*)out;
  vfloat4 vv[8];
  float sj[8];
#pragma unroll
  for (int k = 0; k < 8; ++k) {
    const int f = base + k * 256;
    GLOAD4(vv[k], xv + f);
    GLOAD1(sj[k], scale + f / 784);                  // 784 float4s per (n,c)
  }
  VMWAIT0();
#pragma unroll
  for (int k = 0; k < 8; ++k) {
    const int f = base + k * 256;
    ov[f] = vv[k] * sj[k];
  }
}

extern "C" void kernel_launch(void* const* d_in, const int* in_sizes, int n_in,
                              void* d_out, int out_size, void* d_ws, size_t ws_size,
                              hipStream_t stream) {
  const float* x     = (const float*)d_in[0];
  const float* wg1   = (const float*)d_in[1];
  const float* bn2_g = (const float*)d_in[2];
  const float* bn2_b = (const float*)d_in[3];
  const float* bn2_m = (const float*)d_in[4];
  const float* bn2_v = (const float*)d_in[5];
  const float* wg2   = (const float*)d_in[6];
  const float* bg2   = (const float*)d_in[7];
  const float* beta  = (const float*)d_in[8];
  const float* w1d   = (const float*)d_in[9];
  const float* b1d   = (const float*)d_in[10];
  const float* bn1_g = (const float*)d_in[11];
  const float* bn1_b = (const float*)d_in[12];
  const float* bn1_m = (const float*)d_in[13];
  const float* bn1_v = (const float*)d_in[14];
  float* out = (float*)d_out;

  float* ws      = (float*)d_ws;
  float* partial = ws;                   // 56*32      = 1792
  float* filt    = partial + 1792;       // (slot kept for layout stability)
  float* wt      = filt + 9408;          // 192*192    = 36864
  float* xp      = wt + 36864;           // 64*192*49  = 602112
  float* scale   = xp + 602112;          // 64*192     = 12288

  fused_pre_kernel<<<3272, 256, 0, stream>>>(x, w1d, wg1, bn2_g, bn2_b, bn2_m, bn2_v,
                                             xp, wt, partial);
  scale_kernel<<<64, 256, 0, stream>>>(partial, wg2, bg2, beta, xp, wt, b1d,
                                       bn1_g, bn1_b, bn1_m, bn1_v, scale);
  apply_kernel<<<4704, 256, 0, stream>>>(x, scale, out);
}

// Round 8
// 340.248 us; speedup vs baseline: 2.0701x; 1.0147x over previous
//
#include <hip/hip_runtime.h>
#include <hip/hip_bf16.h>
#include <math.h>

#define CCH 192
#define EPS 1e-5f

typedef float vfloat4 __attribute__((ext_vector_type(4)));

__device__ __constant__ int d_LOWX[32] = {0,0,1,1,0,2,2,1,2,0,3,4,0,1,3,0,1,2,3,4,5,0,1,2,3,4,5,6,1,2,3,4};
__device__ __constant__ int d_LOWY[32] = {0,1,0,1,2,0,1,2,2,3,0,0,4,3,1,5,4,3,2,1,0,6,5,4,3,2,1,0,6,5,4,3};

// asm load: output constraint forces the batch to stay live; asm-volatile order is
// preserved among asm ops, so vmcnt counts over asm-only windows are exact.
#define GLOAD4(dst, addr) \
  asm volatile("global_load_dwordx4 %0, %1, off" : "=v"(dst) : "v"(addr))
#define GLOAD1(dst, addr) \
  asm volatile("global_load_dword %0, %1, off" : "=v"(dst) : "v"(addr))
// counted wait + sched fence (rule #18: consumers must not hoist above the wait)
#define VMWAIT(n) do { \
  asm volatile("s_waitcnt vmcnt(" #n ")" ::: "memory"); \
  __builtin_amdgcn_sched_barrier(0); \
} while (0)

#define ISSUE(buf, base) do { \
  _Pragma("unroll") \
  for (int g = 0; g < 7; ++g) { \
    GLOAD4(buf[2 * g],     (base) + g * 112 + lidx); \
    GLOAD4(buf[2 * g + 1], (base) + g * 112 + 56 + lidx); \
  } \
} while (0)

// reduce one unit's 14 float4s to res[7] (valid at lanes l=0,2,..,12) — registers only,
// NO stores here: the vmem queue between waits must contain asm loads only.
#define REDUCE(buf, res) do { \
  _Pragma("unroll") \
  for (int g = 0; g < 7; ++g) { \
    float s = (buf[2*g].x + buf[2*g].y + buf[2*g].z + buf[2*g].w) + \
              (buf[2*g+1].x + buf[2*g+1].y + buf[2*g+1].z + buf[2*g+1].w); \
    s = act ? s : 0.f; \
    float a = s + __shfl_xor(s, 1); \
    a += __shfl(a, l + 28); \
    a += __shfl(a, l + 14); \
    res[g] = a; \
  } \
} while (0)

// ---------------- K1: fused pre-pass, one launch, three block roles ----------------
//  blocks [0,56):    gate conv rows n=0 -> partial[h][32]
//  blocks [56,200):  pack wt[k*192+c] = w1d[c][k][1]
//  blocks [200,968): PERSISTENT pool: 768 blocks x 4 units, ping-pong pipelined loads,
//                    counted vmcnt over load-only windows, all xp stores at the end.
__global__ __launch_bounds__(256) void fused_pre_kernel(
    const float* __restrict__ x, const float* __restrict__ w1d,
    const float* __restrict__ wg1,
    const float* __restrict__ bn2_g, const float* __restrict__ bn2_b,
    const float* __restrict__ bn2_m, const float* __restrict__ bn2_v,
    float* __restrict__ xp, float* __restrict__ wt, float* __restrict__ partial) {
  const int b = blockIdx.x;
  const int t = threadIdx.x;
  if (b >= 200) {
    // ---- pool role: block owns c-quads q0..q0+3 of batch n (48 quads per n, 48%4==0
    // so no n-straddle). 4 waves, one channel per wave per unit.
    const int ub = b - 200;
    const int n = ub / 12;
    const int q0 = (ub % 12) * 4;
    const int wv = t >> 6, l = t & 63;
    const bool act = l < 56;
    const int lidx = act ? l : 0;
    const vfloat4* xb = (const vfloat4*)(x + (size_t)n * CCH * 3136 + (size_t)wv * 3136);
    const vfloat4* base0 = xb + (size_t)(q0 + 0) * 4 * 784;   // channel quad stride = 4*784 float4
    const vfloat4* base1 = xb + (size_t)(q0 + 1) * 4 * 784;
    const vfloat4* base2 = xb + (size_t)(q0 + 2) * 4 * 784;
    const vfloat4* base3 = xb + (size_t)(q0 + 3) * 4 * 784;
    vfloat4 A[14], B[14];
    float r0[7], r1[7], r2[7], r3[7];
    ISSUE(A, base0);                 // outstanding: 14
    ISSUE(B, base1);                 // outstanding: 28
    VMWAIT(14);                      // u0 loads done; u1 in flight
    REDUCE(A, r0);
    ISSUE(A, base2);                 // outstanding: B(14) + A2(14) = 28
    VMWAIT(14);                      // u1 done; u2 in flight
    REDUCE(B, r1);
    ISSUE(B, base3);                 // outstanding: A2(14) + B2(14) = 28
    VMWAIT(14);                      // u2 done; u3 in flight
    REDUCE(A, r2);
    VMWAIT(0);                       // u3 done
    REDUCE(B, r3);
    if (act && l < 14 && (l & 1) == 0) {
      const int cb = l >> 1;
      float* d0 = xp + ((size_t)n * CCH + (q0 + 0) * 4 + wv) * 49 + cb;
      float* d1 = xp + ((size_t)n * CCH + (q0 + 1) * 4 + wv) * 49 + cb;
      float* d2 = xp + ((size_t)n * CCH + (q0 + 2) * 4 + wv) * 49 + cb;
      float* d3 = xp + ((size_t)n * CCH + (q0 + 3) * 4 + wv) * 49 + cb;
#pragma unroll
      for (int g = 0; g < 7; ++g) {
        d0[g * 7] = r0[g] * (1.f / 64.f);
        d1[g * 7] = r1[g] * (1.f / 64.f);
        d2[g * 7] = r2[g] * (1.f / 64.f);
        d3[g * 7] = r3[g] * (1.f / 64.f);
      }
    }
  } else if (b >= 56) {
    // ---- pack role
    const int i = (b - 56) * 256 + t;             // < 36864
    const int cc = i / CCH, k = i - cc * CCH;
    wt[k * CCH + cc] = w1d[cc * (CCH * 3) + 3 * k + 1];
  } else {
    // ---- gate role (n=0): one h row per block; wave wv owns outputs [8wv,8wv+8)
    const int h = b;
    const int wv = t >> 6, w = t & 63;
    float acc[8];
#pragma unroll
    for (int o = 0; o < 8; ++o) acc[o] = 0.f;
    const float* xrow = x + h * 56;               // x[c*3136 + h*56 + w]
    for (int cc0 = 0; cc0 < CCH; cc0 += 8) {
      float xq[8];
#pragma unroll
      for (int j = 0; j < 8; ++j)
        GLOAD1(xq[j], xrow + (size_t)(cc0 + j) * 3136 + ((w < 56) ? w : 0));
      VMWAIT(0);
#pragma unroll
      for (int j = 0; j < 8; ++j) {
        float xvv = (w < 56) ? xq[j] : 0.f;
#pragma unroll
        for (int o = 0; o < 8; ++o)
          acc[o] += xvv * wg1[(wv * 8 + o) * CCH + cc0 + j];  // uniform -> s_load
      }
    }
#pragma unroll
    for (int o = 0; o < 8; ++o) {
      const int oo = wv * 8 + o;
      float sc = bn2_g[oo] * rsqrtf(bn2_v[oo] + EPS);
      float v = acc[o] * sc + (bn2_b[oo] - bn2_m[oo] * sc);
      v = (w < 56) ? fmaxf(v, 0.f) : 0.f;         // BN offset must not leak into pad lanes
#pragma unroll
      for (int s = 1; s < 64; s <<= 1) v += __shfl_xor(v, s);
      if (w == 0) partial[h * 32 + oo] = v;
    }
  }
}

// ---------------- K2: merged mid+gemv: partial -> xg0 -> param -> filt -> scale ----------
__global__ __launch_bounds__(256) void scale_kernel(
    const float* __restrict__ partial, const float* __restrict__ wg2,
    const float* __restrict__ bg2, const float* __restrict__ beta,
    const float* __restrict__ xp, const float* __restrict__ wt,
    const float* __restrict__ b1d,
    const float* __restrict__ bn1_g, const float* __restrict__ bn1_b,
    const float* __restrict__ bn1_m, const float* __restrict__ bn1_v,
    float* __restrict__ scale) {
  __shared__ float gm[32];
  __shared__ float xg[32];
  __shared__ float param[33];
  __shared__ float Btab[49];
  __shared__ float yl[CCH];
  const int n = blockIdx.x, t = threadIdx.x;
  if (t < 32) {
    float s = 0.f;
    for (int hh = 0; hh < 56; ++hh) s += partial[hh * 32 + t];  // sequential: bit-stable
    gm[t] = s * (1.f / 3136.f);
  }
  if (t < 49) {
    int f = t / 7, tt = t % 7;
    float r = cosf(3.14159265358979323846f * (float)f * ((float)tt + 0.5f) / 7.f) * rsqrtf(7.f);
    Btab[t] = (f == 0) ? r : r * sqrtf(2.f);
  }
  __syncthreads();
  if (t < 32) {
    float a = bg2[t];
    for (int k = 0; k < 32; ++k) a += gm[k] * wg2[t * 32 + k];
    xg[t] = fmaxf(tanhf(a), 0.f) + beta[0];
  }
  __syncthreads();
  if (t == 0) {
    float s = 0.f;
    for (int k = 0; k < 32; ++k) s += xg[k];
    float psum = 0.f;
    param[0] = 0.f;
    for (int i = 0; i < 31; ++i) {
      float p = rintf(xg[i] / s * (float)CCH);  // nearest-even, matches jnp.round
      param[i + 1] = p;
      psum += p;
    }
    param[32] = (float)CCH - psum;
  }
  __syncthreads();
  if (t < CCH) {
    int bi = -1;
    float cf = (float)t;
    for (int i = 0; i < 32; ++i)
      if (cf >= param[i] && cf < param[i + 1]) bi = i;  // last match wins
    int fx = (bi >= 0) ? d_LOWX[bi] : 0;
    int fy = (bi >= 0) ? d_LOWY[bi] : 0;
    const float* xc = xp + ((size_t)n * CCH + t) * 49;
    float s = 0.f;
    for (int cell = 0; cell < 49; ++cell) {
      int a = cell / 7, bb = cell - a * 7;
      float w = Btab[fx * 7 + a] * Btab[fy * 7 + bb];  // same product order as filt build
      s += xc[cell] * ((bi >= 0) ? w : 0.f);
    }
    yl[t] = s;
  }
  __syncthreads();
  if (t < CCH) {
    float acc = b1d[t];
#pragma unroll 8
    for (int k = 0; k < CCH; ++k) acc += yl[k] * wt[k * CCH + t];
    float sc = bn1_g[t] * rsqrtf(bn1_v[t] + EPS);
    float v = (acc - bn1_m[t]) * sc + bn1_b[t];
    scale[n * CCH + t] = 1.f + fmaxf(v, 0.f);
  }
}

// ---------------- K3: out = x * scale[n,c] ----------------
__global__ __launch_bounds__(256) void apply_kernel(
    const float* __restrict__ x, const float* __restrict__ scale,
    float* __restrict__ out) {
  const int base = blockIdx.x * 2048 + threadIdx.x;  // 4704*2048 = 9,633,792 float4s
  const vfloat4* __restrict__ xv = (const vfloat4*)x;
  vfloat4* __restrict__ ov = (vfloat4*)out;
  vfloat4 vv[8];
  float sj[8];
#pragma unroll
  for (int k = 0; k < 8; ++k) {
    const int f = base + k * 256;
    GLOAD4(vv[k], xv + f);
    GLOAD1(sj[k], scale + f / 784);                  // 784 float4s per (n,c)
  }
  VMWAIT(0);
#pragma unroll
  for (int k = 0; k < 8; ++k) {
    const int f = base + k * 256;
    ov[f] = vv[k] * sj[k];
  }
}

extern "C" void kernel_launch(void* const* d_in, const int* in_sizes, int n_in,
                              void* d_out, int out_size, void* d_ws, size_t ws_size,
                              hipStream_t stream) {
  const float* x     = (const float*)d_in[0];
  const float* wg1   = (const float*)d_in[1];
  const float* bn2_g = (const float*)d_in[2];
  const float* bn2_b = (const float*)d_in[3];
  const float* bn2_m = (const float*)d_in[4];
  const float* bn2_v = (const float*)d_in[5];
  const float* wg2   = (const float*)d_in[6];
  const float* bg2   = (const float*)d_in[7];
  const float* beta  = (const float*)d_in[8];
  const float* w1d   = (const float*)d_in[9];
  const float* b1d   = (const float*)d_in[10];
  const float* bn1_g = (const float*)d_in[11];
  const float* bn1_b = (const float*)d_in[12];
  const float* bn1_m = (const float*)d_in[13];
  const float* bn1_v = (const float*)d_in[14];
  float* out = (float*)d_out;

  float* ws      = (float*)d_ws;
  float* partial = ws;                   // 56*32      = 1792
  float* filt    = partial + 1792;       // (slot kept for layout stability)
  float* wt      = filt + 9408;          // 192*192    = 36864
  float* xp      = wt + 36864;           // 64*192*49  = 602112
  float* scale   = xp + 602112;          // 64*192     = 12288

  fused_pre_kernel<<<968, 256, 0, stream>>>(x, w1d, wg1, bn2_g, bn2_b, bn2_m, bn2_v,
                                            xp, wt, partial);
  scale_kernel<<<64, 256, 0, stream>>>(partial, wg2, bg2, beta, xp, wt, b1d,
                                       bn1_g, bn1_b, bn1_m, bn1_v, scale);
  apply_kernel<<<4704, 256, 0, stream>>>(x, scale, out);
}

// Round 9
// 339.789 us; speedup vs baseline: 2.0729x; 1.0014x over previous
//
#include <hip/hip_runtime.h>
#include <hip/hip_bf16.h>
#include <math.h>

#define CCH 192
#define EPS 1e-5f

typedef float vfloat4 __attribute__((ext_vector_type(4)));

__device__ __constant__ int d_LOWX[32] = {0,0,1,1,0,2,2,1,2,0,3,4,0,1,3,0,1,2,3,4,5,0,1,2,3,4,5,6,1,2,3,4};
__device__ __constant__ int d_LOWY[32] = {0,1,0,1,2,0,1,2,2,3,0,0,4,3,1,5,4,3,2,1,0,6,5,4,3,2,1,0,6,5,4,3};

// asm load: output constraint forces the batch to stay live; asm-volatile order is
// preserved among asm ops, so vmcnt counts over asm-only windows are exact.
#define GLOAD4(dst, addr) \
  asm volatile("global_load_dwordx4 %0, %1, off" : "=v"(dst) : "v"(addr))
#define GLOAD1(dst, addr) \
  asm volatile("global_load_dword %0, %1, off" : "=v"(dst) : "v"(addr))
#define VMWAIT(n) do { \
  asm volatile("s_waitcnt vmcnt(" #n ")" ::: "memory"); \
  __builtin_amdgcn_sched_barrier(0); \
} while (0)

#define ISSUE(buf, base) do { \
  _Pragma("unroll") \
  for (int g = 0; g < 7; ++g) { \
    GLOAD4(buf[2 * g],     (base) + g * 112 + lidx); \
    GLOAD4(buf[2 * g + 1], (base) + g * 112 + 56 + lidx); \
  } \
} while (0)

// reduce one unit's 14 float4s to res[7] (valid at lanes l=0,2,..,12) — registers only,
// NO stores here: the vmem queue between waits must contain asm loads only.
#define REDUCE(buf, res) do { \
  _Pragma("unroll") \
  for (int g = 0; g < 7; ++g) { \
    float s = (buf[2*g].x + buf[2*g].y + buf[2*g].z + buf[2*g].w) + \
              (buf[2*g+1].x + buf[2*g+1].y + buf[2*g+1].z + buf[2*g+1].w); \
    s = act ? s : 0.f; \
    float a = s + __shfl_xor(s, 1); \
    a += __shfl(a, l + 28); \
    a += __shfl(a, l + 14); \
    res[g] = a; \
  } \
} while (0)

// ---------------- K1: fused pre-pass (unchanged from passing round-8 version) ----------
//  blocks [0,56):    gate conv rows n=0 -> partial[h][32]
//  blocks [56,200):  pack wt[k*192+c] = w1d[c][k][1]
//  blocks [200,968): persistent pool: 768 blocks x 4 units, ping-pong pipelined loads
__global__ __launch_bounds__(256) void fused_pre_kernel(
    const float* __restrict__ x, const float* __restrict__ w1d,
    const float* __restrict__ wg1,
    const float* __restrict__ bn2_g, const float* __restrict__ bn2_b,
    const float* __restrict__ bn2_m, const float* __restrict__ bn2_v,
    float* __restrict__ xp, float* __restrict__ wt, float* __restrict__ partial) {
  const int b = blockIdx.x;
  const int t = threadIdx.x;
  if (b >= 200) {
    const int ub = b - 200;
    const int n = ub / 12;
    const int q0 = (ub % 12) * 4;
    const int wv = t >> 6, l = t & 63;
    const bool act = l < 56;
    const int lidx = act ? l : 0;
    const vfloat4* xb = (const vfloat4*)(x + (size_t)n * CCH * 3136 + (size_t)wv * 3136);
    const vfloat4* base0 = xb + (size_t)(q0 + 0) * 4 * 784;
    const vfloat4* base1 = xb + (size_t)(q0 + 1) * 4 * 784;
    const vfloat4* base2 = xb + (size_t)(q0 + 2) * 4 * 784;
    const vfloat4* base3 = xb + (size_t)(q0 + 3) * 4 * 784;
    vfloat4 A[14], B[14];
    float r0[7], r1[7], r2[7], r3[7];
    ISSUE(A, base0);                 // outstanding: 14
    ISSUE(B, base1);                 // outstanding: 28
    VMWAIT(14);                      // u0 loads done; u1 in flight
    REDUCE(A, r0);
    ISSUE(A, base2);
    VMWAIT(14);                      // u1 done; u2 in flight
    REDUCE(B, r1);
    ISSUE(B, base3);
    VMWAIT(14);                      // u2 done; u3 in flight
    REDUCE(A, r2);
    VMWAIT(0);                       // u3 done
    REDUCE(B, r3);
    if (act && l < 14 && (l & 1) == 0) {
      const int cb = l >> 1;
      float* d0 = xp + ((size_t)n * CCH + (q0 + 0) * 4 + wv) * 49 + cb;
      float* d1 = xp + ((size_t)n * CCH + (q0 + 1) * 4 + wv) * 49 + cb;
      float* d2 = xp + ((size_t)n * CCH + (q0 + 2) * 4 + wv) * 49 + cb;
      float* d3 = xp + ((size_t)n * CCH + (q0 + 3) * 4 + wv) * 49 + cb;
#pragma unroll
      for (int g = 0; g < 7; ++g) {
        d0[g * 7] = r0[g] * (1.f / 64.f);
        d1[g * 7] = r1[g] * (1.f / 64.f);
        d2[g * 7] = r2[g] * (1.f / 64.f);
        d3[g * 7] = r3[g] * (1.f / 64.f);
      }
    }
  } else if (b >= 56) {
    const int i = (b - 56) * 256 + t;             // < 36864
    const int cc = i / CCH, k = i - cc * CCH;
    wt[k * CCH + cc] = w1d[cc * (CCH * 3) + 3 * k + 1];
  } else {
    const int h = b;
    const int wv = t >> 6, w = t & 63;
    float acc[8];
#pragma unroll
    for (int o = 0; o < 8; ++o) acc[o] = 0.f;
    const float* xrow = x + h * 56;               // x[c*3136 + h*56 + w]
    for (int cc0 = 0; cc0 < CCH; cc0 += 8) {
      float xq[8];
#pragma unroll
      for (int j = 0; j < 8; ++j)
        GLOAD1(xq[j], xrow + (size_t)(cc0 + j) * 3136 + ((w < 56) ? w : 0));
      VMWAIT(0);
#pragma unroll
      for (int j = 0; j < 8; ++j) {
        float xvv = (w < 56) ? xq[j] : 0.f;
#pragma unroll
        for (int o = 0; o < 8; ++o)
          acc[o] += xvv * wg1[(wv * 8 + o) * CCH + cc0 + j];  // uniform -> s_load
      }
    }
#pragma unroll
    for (int o = 0; o < 8; ++o) {
      const int oo = wv * 8 + o;
      float sc = bn2_g[oo] * rsqrtf(bn2_v[oo] + EPS);
      float v = acc[o] * sc + (bn2_b[oo] - bn2_m[oo] * sc);
      v = (w < 56) ? fmaxf(v, 0.f) : 0.f;         // BN offset must not leak into pad lanes
#pragma unroll
      for (int s = 1; s < 64; s <<= 1) v += __shfl_xor(v, s);
      if (w == 0) partial[h * 32 + oo] = v;
    }
  }
}

// ---------------- K2: merged scale+apply.  grid 256 = 4 blocks per n. ----------------
// Phase A: recompute scale[n] redundantly (bit-identical sequential arithmetic —
// the rintf partition boundary must not move) into LDS.  Redundant wt/xp reads hit L2/L3.
// Phase B: apply this block's quarter of x[n] (48 channels, 147 float4/thread, 8-deep).
__global__ __launch_bounds__(256) void scale_apply_kernel(
    const float* __restrict__ partial, const float* __restrict__ wg2,
    const float* __restrict__ bg2, const float* __restrict__ beta,
    const float* __restrict__ xp, const float* __restrict__ wt,
    const float* __restrict__ b1d,
    const float* __restrict__ bn1_g, const float* __restrict__ bn1_b,
    const float* __restrict__ bn1_m, const float* __restrict__ bn1_v,
    const float* __restrict__ x, float* __restrict__ out) {
  __shared__ float gm[32];
  __shared__ float xg[32];
  __shared__ float param[33];
  __shared__ float Btab[49];
  __shared__ float yl[CCH];
  __shared__ float sl[CCH];
  const int blk = blockIdx.x, t = threadIdx.x;
  const int n = blk >> 2, qi = blk & 3;
  // ---- phase A (identical arithmetic to the passing scale_kernel) ----
  if (t < 32) {
    float s = 0.f;
    for (int hh = 0; hh < 56; ++hh) s += partial[hh * 32 + t];  // sequential: bit-stable
    gm[t] = s * (1.f / 3136.f);
  }
  if (t < 49) {
    int f = t / 7, tt = t % 7;
    float r = cosf(3.14159265358979323846f * (float)f * ((float)tt + 0.5f) / 7.f) * rsqrtf(7.f);
    Btab[t] = (f == 0) ? r : r * sqrtf(2.f);
  }
  __syncthreads();
  if (t < 32) {
    float a = bg2[t];
    for (int k = 0; k < 32; ++k) a += gm[k] * wg2[t * 32 + k];
    xg[t] = fmaxf(tanhf(a), 0.f) + beta[0];
  }
  __syncthreads();
  if (t == 0) {
    float s = 0.f;
    for (int k = 0; k < 32; ++k) s += xg[k];
    float psum = 0.f;
    param[0] = 0.f;
    for (int i = 0; i < 31; ++i) {
      float p = rintf(xg[i] / s * (float)CCH);  // nearest-even, matches jnp.round
      param[i + 1] = p;
      psum += p;
    }
    param[32] = (float)CCH - psum;
  }
  __syncthreads();
  if (t < CCH) {
    int bi = -1;
    float cf = (float)t;
    for (int i = 0; i < 32; ++i)
      if (cf >= param[i] && cf < param[i + 1]) bi = i;  // last match wins
    int fx = (bi >= 0) ? d_LOWX[bi] : 0;
    int fy = (bi >= 0) ? d_LOWY[bi] : 0;
    const float* xc = xp + ((size_t)n * CCH + t) * 49;
    float s = 0.f;
    for (int cell = 0; cell < 49; ++cell) {
      int a = cell / 7, bb = cell - a * 7;
      float w = Btab[fx * 7 + a] * Btab[fy * 7 + bb];  // same product order as filt build
      s += xc[cell] * ((bi >= 0) ? w : 0.f);
    }
    yl[t] = s;
  }
  __syncthreads();
  if (t < CCH) {
    float acc = b1d[t];
#pragma unroll 8
    for (int k = 0; k < CCH; ++k) acc += yl[k] * wt[k * CCH + t];
    float sc = bn1_g[t] * rsqrtf(bn1_v[t] + EPS);
    float v = (acc - bn1_m[t]) * sc + bn1_b[t];
    sl[t] = 1.f + fmaxf(v, 0.f);
  }
  __syncthreads();
  // ---- phase B: apply quarter qi of batch n ----
  // per n: 784*192 = 150528 float4s; per quarter: 37632 = 147*256 (exactly 48 channels)
  const vfloat4* __restrict__ xv = (const vfloat4*)x;
  vfloat4* __restrict__ ov = (vfloat4*)out;
  const int off0 = qi * 37632 + t;               // offset within n, float4 units
  const size_t base = (size_t)n * 150528 + off0;
#pragma unroll
  for (int B = 0; B < 18; ++B) {
    vfloat4 vv[8];
#pragma unroll
    for (int j = 0; j < 8; ++j) vv[j] = xv[base + (B * 8 + j) * 256];
#pragma unroll
    for (int j = 0; j < 8; ++j) {
      const int off = off0 + (B * 8 + j) * 256;
      ov[base + (B * 8 + j) * 256] = vv[j] * sl[off / 784];
    }
  }
#pragma unroll
  for (int k = 144; k < 147; ++k) {
    const int off = off0 + k * 256;
    ov[base + k * 256] = xv[base + k * 256] * sl[off / 784];
  }
}

extern "C" void kernel_launch(void* const* d_in, const int* in_sizes, int n_in,
                              void* d_out, int out_size, void* d_ws, size_t ws_size,
                              hipStream_t stream) {
  const float* x     = (const float*)d_in[0];
  const float* wg1   = (const float*)d_in[1];
  const float* bn2_g = (const float*)d_in[2];
  const float* bn2_b = (const float*)d_in[3];
  const float* bn2_m = (const float*)d_in[4];
  const float* bn2_v = (const float*)d_in[5];
  const float* wg2   = (const float*)d_in[6];
  const float* bg2   = (const float*)d_in[7];
  const float* beta  = (const float*)d_in[8];
  const float* w1d   = (const float*)d_in[9];
  const float* b1d   = (const float*)d_in[10];
  const float* bn1_g = (const float*)d_in[11];
  const float* bn1_b = (const float*)d_in[12];
  const float* bn1_m = (const float*)d_in[13];
  const float* bn1_v = (const float*)d_in[14];
  float* out = (float*)d_out;

  float* ws      = (float*)d_ws;
  float* partial = ws;                   // 56*32      = 1792
  float* filt    = partial + 1792;       // (slot kept for layout stability)
  float* wt      = filt + 9408;          // 192*192    = 36864
  float* xp      = wt + 36864;           // 64*192*49  = 602112

  fused_pre_kernel<<<968, 256, 0, stream>>>(x, w1d, wg1, bn2_g, bn2_b, bn2_m, bn2_v,
                                            xp, wt, partial);
  scale_apply_kernel<<<256, 256, 0, stream>>>(partial, wg2, bg2, beta, xp, wt, b1d,
                                              bn1_g, bn1_b, bn1_m, bn1_v, x, out);
}